// Round 2
// baseline (692.286 us; speedup 1.0000x reference)
//
#include <hip/hip_runtime.h>

#define B 32
#define N 512
#define P 8
#define H 300
#define EPSN 1e-12f

#define NT 64                    // n rows per block tile
#define KT 64                    // k cols per block tile
#define HCH 32                   // h per chunk
#define NCHUNK ((H + HCH - 1) / HCH)   // 10
#define KC ((H + KT - 1) / KT)         // 5

#define SA_STRIDE 36             // 32 + 4 pad (keeps 16B alignment)
#define SW_STRIDE 68             // 64 + 4 pad

__device__ __forceinline__ void fma4(float4& acc, float s, const float4& wv) {
    acc.x += s * wv.x;
    acc.y += s * wv.y;
    acc.z += s * wv.z;
    acc.w += s * wv.w;
}

__global__ __launch_bounds__(256)
void nsm_scores_kernel(const float* __restrict__ node_attr,
                       const float* __restrict__ instruction,
                       const float* __restrict__ nps,
                       const float* __restrict__ W_node,
                       const float* __restrict__ w_state,
                       float* __restrict__ scores)
{
    __shared__ float sA[NT * SA_STRIDE];   // A[n_local][hh], pre-scaled by instruction
    __shared__ float sW[HCH * SW_STRIDE];  // W[hh][k_local]
    __shared__ float sI[320];              // instruction row, zero-padded

    const int t  = threadIdx.x;
    const int b  = blockIdx.z;
    const int n0 = blockIdx.y * NT;
    const int k0 = blockIdx.x * KT;
    const int tx = t & 15;
    const int ty = t >> 4;

    // stage instruction row once
    for (int idx = t; idx < 320; idx += 256)
        sI[idx] = (idx < H) ? instruction[b * H + idx] : 0.f;
    __syncthreads();

    float4 S1[4], S2[4];
    #pragma unroll
    for (int i = 0; i < 4; ++i) {
        S1[i] = make_float4(0.f, 0.f, 0.f, 0.f);
        S2[i] = make_float4(0.f, 0.f, 0.f, 0.f);
    }

    for (int p = 0; p < P; ++p) {
        float4 acc[4];
        #pragma unroll
        for (int i = 0; i < 4; ++i) acc[i] = make_float4(0.f, 0.f, 0.f, 0.f);

        for (int hc = 0; hc < NCHUNK; ++hc) {
            const int h0 = hc * HCH;

            // stage A: 64 rows x 32 h = 512 float4, 2 per thread
            #pragma unroll
            for (int r = 0; r < 2; ++r) {
                int idx = t + r * 256;
                int ns  = idx >> 3;
                int h4  = idx & 7;
                int h   = h0 + h4 * 4;
                float4 v = make_float4(0.f, 0.f, 0.f, 0.f);
                if (h + 3 < H) {
                    v = *(const float4*)&node_attr[((size_t)((b * N + n0 + ns) * P + p)) * H + h];
                    v.x *= sI[h]; v.y *= sI[h + 1]; v.z *= sI[h + 2]; v.w *= sI[h + 3];
                }
                *(float4*)&sA[ns * SA_STRIDE + h4 * 4] = v;
            }
            // stage W: 32 h x 64 k = 512 float4, 2 per thread
            #pragma unroll
            for (int r = 0; r < 2; ++r) {
                int idx = t + r * 256;
                int hs  = idx >> 4;
                int k4  = idx & 15;
                int h   = h0 + hs;
                int k   = k0 + k4 * 4;
                float4 v = make_float4(0.f, 0.f, 0.f, 0.f);
                if (h < H && k + 3 < H)
                    v = *(const float4*)&W_node[((size_t)(p * H + h)) * H + k];
                *(float4*)&sW[hs * SW_STRIDE + k4 * 4] = v;
            }
            __syncthreads();

            #pragma unroll
            for (int h4 = 0; h4 < 8; ++h4) {
                float4 a[4], w[4];
                #pragma unroll
                for (int i = 0; i < 4; ++i)
                    a[i] = *(float4*)&sA[(ty * 4 + i) * SA_STRIDE + h4 * 4];
                #pragma unroll
                for (int j = 0; j < 4; ++j)
                    w[j] = *(float4*)&sW[(h4 * 4 + j) * SW_STRIDE + tx * 4];
                #pragma unroll
                for (int i = 0; i < 4; ++i) {
                    fma4(acc[i], a[i].x, w[0]);
                    fma4(acc[i], a[i].y, w[1]);
                    fma4(acc[i], a[i].z, w[2]);
                    fma4(acc[i], a[i].w, w[3]);
                }
            }
            __syncthreads();
        }

        // fold this p into S1/S2 (z = sim * acc)
        const float sim = nps[b * P + p];
        #pragma unroll
        for (int i = 0; i < 4; ++i) {
            float4 z;
            z.x = sim * acc[i].x; z.y = sim * acc[i].y;
            z.z = sim * acc[i].z; z.w = sim * acc[i].w;
            S1[i].x += z.x; S1[i].y += z.y; S1[i].z += z.z; S1[i].w += z.w;
            S2[i].x += z.x * z.x; S2[i].y += z.y * z.y;
            S2[i].z += z.z * z.z; S2[i].w += z.w * z.w;
        }
    }

    // finalize: v = S1 / max(sqrt(S2), eps); elu; dot with w_state; reduce over k
    #pragma unroll
    for (int i = 0; i < 4; ++i) {
        float s1v[4] = { S1[i].x, S1[i].y, S1[i].z, S1[i].w };
        float s2v[4] = { S2[i].x, S2[i].y, S2[i].z, S2[i].w };
        float part = 0.f;
        #pragma unroll
        for (int c = 0; c < 4; ++c) {
            int k = k0 + tx * 4 + c;
            if (k < H) {
                float denom = fmaxf(sqrtf(s2v[c]), EPSN);
                float v = s1v[c] / denom;
                float e = v > 0.f ? v : expm1f(v);
                part += e * w_state[k];
            }
        }
        part += __shfl_xor(part, 1, 16);
        part += __shfl_xor(part, 2, 16);
        part += __shfl_xor(part, 4, 16);
        part += __shfl_xor(part, 8, 16);
        if (tx == 0)
            atomicAdd(&scores[b * N + n0 + ty * 4 + i], part);
    }
}

__global__ __launch_bounds__(256)
void nsm_softmax_kernel(float* __restrict__ out, const float* __restrict__ mask)
{
    __shared__ float redm[4];
    __shared__ float reds[4];
    const int b = blockIdx.x;
    const int t = threadIdx.x;

    float v0 = out[b * N + t]       + mask[b * N + t];
    float v1 = out[b * N + 256 + t] + mask[b * N + 256 + t];

    float m = fmaxf(v0, v1);
    m = fmaxf(m, __shfl_xor(m, 1, 64));
    m = fmaxf(m, __shfl_xor(m, 2, 64));
    m = fmaxf(m, __shfl_xor(m, 4, 64));
    m = fmaxf(m, __shfl_xor(m, 8, 64));
    m = fmaxf(m, __shfl_xor(m, 16, 64));
    m = fmaxf(m, __shfl_xor(m, 32, 64));
    const int wave = t >> 6;
    const int lane = t & 63;
    if (lane == 0) redm[wave] = m;
    __syncthreads();
    m = fmaxf(fmaxf(redm[0], redm[1]), fmaxf(redm[2], redm[3]));

    float e0 = expf(v0 - m);
    float e1 = expf(v1 - m);
    float s = e0 + e1;
    s += __shfl_xor(s, 1, 64);
    s += __shfl_xor(s, 2, 64);
    s += __shfl_xor(s, 4, 64);
    s += __shfl_xor(s, 8, 64);
    s += __shfl_xor(s, 16, 64);
    s += __shfl_xor(s, 32, 64);
    if (lane == 0) reds[wave] = s;
    __syncthreads();
    s = reds[0] + reds[1] + reds[2] + reds[3];

    out[b * N + t]       = e0 / s;
    out[b * N + 256 + t] = e1 / s;
}

extern "C" void kernel_launch(void* const* d_in, const int* in_sizes, int n_in,
                              void* d_out, int out_size, void* d_ws, size_t ws_size,
                              hipStream_t stream)
{
    const float* node_attr   = (const float*)d_in[0];
    // d_in[1] edge_attr  : unused for ins_id = 0
    const float* instruction = (const float*)d_in[2];
    // d_in[3] distribution: unused for ins_id = 0
    // d_in[4] ins_id      : always 0 in this problem
    const float* nps         = (const float*)d_in[5];
    const float* node_mask   = (const float*)d_in[6];
    const float* W_node      = (const float*)d_in[7];
    const float* w_state     = (const float*)d_in[8];
    float* out = (float*)d_out;

    // d_out doubles as the scores accumulator (B*N floats); zero it first.
    (void)hipMemsetAsync(out, 0, (size_t)B * N * sizeof(float), stream);

    dim3 grid(KC, N / NT, B);   // (5, 8, 32)
    nsm_scores_kernel<<<grid, 256, 0, stream>>>(node_attr, instruction, nps,
                                                W_node, w_state, out);
    nsm_softmax_kernel<<<dim3(B), 256, 0, stream>>>(out, node_mask);
}

// Round 3
// 376.715 us; speedup vs baseline: 1.8377x; 1.8377x over previous
//
#include <hip/hip_runtime.h>

#define B 32
#define N 512
#define P 8
#define H 300
#define HP 320
#define EPSN 1e-12f
#define NT 32
#define SA_STRIDE 328        // bf16 elems per LDS row: 320 + 8 pad (bank decorrelation)

typedef __attribute__((ext_vector_type(8))) short bf16x8;
typedef __attribute__((ext_vector_type(4))) float f32x4;

__device__ __forceinline__ unsigned short f2bf(float f) {
    unsigned int u = __float_as_uint(f);
    u += 0x7FFFu + ((u >> 16) & 1u);      // round-to-nearest-even
    return (unsigned short)(u >> 16);
}
__device__ __forceinline__ float bf2f(unsigned short h) {
    return __uint_as_float(((unsigned int)h) << 16);
}

// Pre-convert W (P,H,H fp32) into MFMA-B-fragment-ordered bf16 hi/lo planes.
// Fragment block fb = (p*10 + ht)*20 + kt holds lanes' 8 k-slice elements
// contiguous: off = fb*512 + lane*8 + j, where h = ht*32+(lane>>4)*8+j,
// k = kt*16+(lane&15). A wave's fragment load is then one coalesced dwordx4.
__global__ __launch_bounds__(256)
void nsm_prep_w(const float* __restrict__ W,
                unsigned short* __restrict__ whi,
                unsigned short* __restrict__ wlo)
{
    const int gid  = blockIdx.x * 256 + threadIdx.x;
    const int fb   = gid >> 6;            // 0..1599
    const int lane = gid & 63;
    const int p  = fb / 200;
    const int rm = fb % 200;
    const int ht = rm / 20;
    const int kt = rm % 20;
    const int k  = kt * 16 + (lane & 15);
    const int h0 = ht * 32 + (lane >> 4) * 8;

    bf16x8 hv, lv;
    #pragma unroll
    for (int j = 0; j < 8; ++j) {
        int h = h0 + j;
        float wv = (h < H && k < H) ? W[((size_t)p * H + h) * H + k] : 0.f;
        unsigned short hb = f2bf(wv);
        hv[j] = (short)hb;
        lv[j] = (short)f2bf(wv - bf2f(hb));
    }
    size_t off = (size_t)fb * 512 + (size_t)lane * 8;
    *(bf16x8*)(whi + off) = hv;
    *(bf16x8*)(wlo + off) = lv;
}

// One block = 32 n-rows x full k (320 padded). 4 waves; wave w owns k-range
// [80w, 80w+80) = 5 k-tiles of 16, both 16-row n-tiles. Split-bf16: 3 MFMAs
// per logical one (ah*wh + al*wh + ah*wl). S1/S2 accumulate over P in regs.
__global__ __launch_bounds__(256, 2)
void nsm_scores_mfma(const float* __restrict__ node_attr,
                     const float* __restrict__ instruction,
                     const float* __restrict__ nps,
                     const unsigned short* __restrict__ whi,
                     const unsigned short* __restrict__ wlo,
                     const float* __restrict__ w_state,
                     float* __restrict__ scores)
{
    __shared__ unsigned short sAh[NT * SA_STRIDE];
    __shared__ unsigned short sAl[NT * SA_STRIDE];
    __shared__ float sI[HP];

    const int t  = threadIdx.x;
    const int b  = blockIdx.y;
    const int n0 = blockIdx.x * NT;
    const int w  = t >> 6;                // wave 0..3
    const int l  = t & 63;

    for (int idx = t; idx < HP; idx += 256)
        sI[idx] = (idx < H) ? instruction[b * H + idx] : 0.f;

    f32x4 S1[2][5], S2[2][5];
    #pragma unroll
    for (int nt = 0; nt < 2; ++nt)
        #pragma unroll
        for (int kt = 0; kt < 5; ++kt) {
            S1[nt][kt] = (f32x4){0.f, 0.f, 0.f, 0.f};
            S2[nt][kt] = (f32x4){0.f, 0.f, 0.f, 0.f};
        }

    const int r  = t >> 3;                // staging row 0..31
    const int cs = t & 7;                 // staging col-slot

    for (int p = 0; p < P; ++p) {
        __syncthreads();                  // prev compute done (and sI visible at p=0)

        // ---- stage A: 32 rows x 300 fp32, scale by instruction, split hi/lo ----
        const float* srcA = node_attr + ((size_t)((b * N + n0 + r) * P + p)) * H;
        unsigned short* dh = &sAh[r * SA_STRIDE];
        unsigned short* dl = &sAl[r * SA_STRIDE];
        #pragma unroll
        for (int i = 0; i < 10; ++i) {
            int s = cs + i * 8;           // float4 slot 0..79 (75..79 -> zero pad)
            int h = s * 4;
            float4 v = make_float4(0.f, 0.f, 0.f, 0.f);
            if (s < 75) {
                v = *(const float4*)(srcA + h);
                float4 sc = *(const float4*)&sI[h];
                v.x *= sc.x; v.y *= sc.y; v.z *= sc.z; v.w *= sc.w;
            }
            unsigned short h0b = f2bf(v.x), h1b = f2bf(v.y);
            unsigned short h2b = f2bf(v.z), h3b = f2bf(v.w);
            unsigned short l0b = f2bf(v.x - bf2f(h0b)), l1b = f2bf(v.y - bf2f(h1b));
            unsigned short l2b = f2bf(v.z - bf2f(h2b)), l3b = f2bf(v.w - bf2f(h3b));
            *(uint2*)(dh + h) = make_uint2((unsigned)h0b | ((unsigned)h1b << 16),
                                           (unsigned)h2b | ((unsigned)h3b << 16));
            *(uint2*)(dl + h) = make_uint2((unsigned)l0b | ((unsigned)l1b << 16),
                                           (unsigned)l2b | ((unsigned)l3b << 16));
        }
        __syncthreads();

        // ---- MFMA over h in 10 chunks of 32 ----
        f32x4 acc[2][5];
        #pragma unroll
        for (int nt = 0; nt < 2; ++nt)
            #pragma unroll
            for (int kt = 0; kt < 5; ++kt)
                acc[nt][kt] = (f32x4){0.f, 0.f, 0.f, 0.f};

        for (int ht = 0; ht < 10; ++ht) {
            bf16x8 ah[2], al[2];
            const int hoff = ht * 32 + (l >> 4) * 8;
            #pragma unroll
            for (int nt = 0; nt < 2; ++nt) {
                const int row = nt * 16 + (l & 15);
                ah[nt] = *(const bf16x8*)&sAh[row * SA_STRIDE + hoff];
                al[nt] = *(const bf16x8*)&sAl[row * SA_STRIDE + hoff];
            }
            #pragma unroll
            for (int kt = 0; kt < 5; ++kt) {
                size_t off = ((size_t)(p * 10 + ht) * 20 + (w * 5 + kt)) * 512
                           + (size_t)l * 8;
                bf16x8 bh = *(const bf16x8*)(whi + off);
                bf16x8 bl = *(const bf16x8*)(wlo + off);
                #pragma unroll
                for (int nt = 0; nt < 2; ++nt) {
                    acc[nt][kt] = __builtin_amdgcn_mfma_f32_16x16x32_bf16(ah[nt], bh, acc[nt][kt], 0, 0, 0);
                    acc[nt][kt] = __builtin_amdgcn_mfma_f32_16x16x32_bf16(al[nt], bh, acc[nt][kt], 0, 0, 0);
                    acc[nt][kt] = __builtin_amdgcn_mfma_f32_16x16x32_bf16(ah[nt], bl, acc[nt][kt], 0, 0, 0);
                }
            }
        }

        // ---- fold p into S1/S2 ----
        const float sim = nps[b * P + p];
        #pragma unroll
        for (int nt = 0; nt < 2; ++nt)
            #pragma unroll
            for (int kt = 0; kt < 5; ++kt) {
                f32x4 z = acc[nt][kt] * sim;
                S1[nt][kt] += z;
                S2[nt][kt] += z * z;
            }
    }

    // ---- epilogue: normalize over P, elu, dot w_state, reduce over k ----
    // C/D layout: col(k) = l&15, row(n) = (l>>4)*4 + j   [m89]
    #pragma unroll
    for (int nt = 0; nt < 2; ++nt) {
        #pragma unroll
        for (int j = 0; j < 4; ++j) {
            float part = 0.f;
            #pragma unroll
            for (int kt = 0; kt < 5; ++kt) {
                int k = w * 80 + kt * 16 + (l & 15);
                if (k < H) {
                    float s1 = S1[nt][kt][j];
                    float s2 = S2[nt][kt][j];
                    float denom = fmaxf(sqrtf(s2), EPSN);
                    float v = s1 / denom;
                    float e = v > 0.f ? v : expm1f(v);
                    part += e * w_state[k];
                }
            }
            part += __shfl_xor(part, 1, 16);
            part += __shfl_xor(part, 2, 16);
            part += __shfl_xor(part, 4, 16);
            part += __shfl_xor(part, 8, 16);
            if ((l & 15) == 0)
                atomicAdd(&scores[b * N + n0 + nt * 16 + (l >> 4) * 4 + j], part);
        }
    }
}

__global__ __launch_bounds__(256)
void nsm_softmax_kernel(float* __restrict__ out, const float* __restrict__ mask)
{
    __shared__ float redm[4];
    __shared__ float reds[4];
    const int b = blockIdx.x;
    const int t = threadIdx.x;

    float v0 = out[b * N + t]       + mask[b * N + t];
    float v1 = out[b * N + 256 + t] + mask[b * N + 256 + t];

    float m = fmaxf(v0, v1);
    m = fmaxf(m, __shfl_xor(m, 1, 64));
    m = fmaxf(m, __shfl_xor(m, 2, 64));
    m = fmaxf(m, __shfl_xor(m, 4, 64));
    m = fmaxf(m, __shfl_xor(m, 8, 64));
    m = fmaxf(m, __shfl_xor(m, 16, 64));
    m = fmaxf(m, __shfl_xor(m, 32, 64));
    const int wave = t >> 6;
    const int lane = t & 63;
    if (lane == 0) redm[wave] = m;
    __syncthreads();
    m = fmaxf(fmaxf(redm[0], redm[1]), fmaxf(redm[2], redm[3]));

    float e0 = expf(v0 - m);
    float e1 = expf(v1 - m);
    float s = e0 + e1;
    s += __shfl_xor(s, 1, 64);
    s += __shfl_xor(s, 2, 64);
    s += __shfl_xor(s, 4, 64);
    s += __shfl_xor(s, 8, 64);
    s += __shfl_xor(s, 16, 64);
    s += __shfl_xor(s, 32, 64);
    if (lane == 0) reds[wave] = s;
    __syncthreads();
    s = reds[0] + reds[1] + reds[2] + reds[3];

    out[b * N + t]       = e0 / s;
    out[b * N + 256 + t] = e1 / s;
}

extern "C" void kernel_launch(void* const* d_in, const int* in_sizes, int n_in,
                              void* d_out, int out_size, void* d_ws, size_t ws_size,
                              hipStream_t stream)
{
    const float* node_attr   = (const float*)d_in[0];
    const float* instruction = (const float*)d_in[2];
    const float* nps         = (const float*)d_in[5];
    const float* node_mask   = (const float*)d_in[6];
    const float* W_node      = (const float*)d_in[7];
    const float* w_state     = (const float*)d_in[8];
    float* out = (float*)d_out;

    unsigned short* whi = (unsigned short*)d_ws;          // 1600*512 bf16 = 1.64 MB
    unsigned short* wlo = whi + 1600 * 512;               // second plane

    nsm_prep_w<<<dim3(400), 256, 0, stream>>>(W_node, whi, wlo);

    (void)hipMemsetAsync(out, 0, (size_t)B * N * sizeof(float), stream);

    dim3 grid(N / NT, B);   // (16, 32) = 512 blocks, 2/CU
    nsm_scores_mfma<<<grid, 256, 0, stream>>>(node_attr, instruction, nps,
                                              whi, wlo, w_state, out);
    nsm_softmax_kernel<<<dim3(B), 256, 0, stream>>>(out, node_mask);
}

// Round 4
// 335.193 us; speedup vs baseline: 2.0653x; 1.1239x over previous
//
#include <hip/hip_runtime.h>

#define B 32
#define N 512
#define P 8
#define H 300
#define HP 320
#define EPSN 1e-12f
#define NT 32                 // n rows per block
#define NB (N / NT)           // 16 n-blocks
#define SAP 328               // LDS row stride (fp16 elems) in prep_a

typedef _Float16 f16x8 __attribute__((ext_vector_type(8)));
typedef float f32x4 __attribute__((ext_vector_type(4)));

// ---------------- prep_w: W (P,H,H fp32) -> fragment-ordered fp16 ----------------
// Fragment block fb = (p*10 + ht)*20 + kt; elem off = fb*512 + lane*8 + j,
// where h = ht*32 + (lane>>4)*8 + j, k = kt*16 + (lane&15).
__global__ __launch_bounds__(256)
void nsm_prep_w(const float* __restrict__ W, _Float16* __restrict__ wfrag)
{
    const int gid  = blockIdx.x * 256 + threadIdx.x;
    const int fb   = gid >> 6;            // 0..1599
    const int lane = gid & 63;
    const int p  = fb / 200;
    const int rm = fb % 200;
    const int ht = rm / 20;
    const int kt = rm % 20;
    const int k  = kt * 16 + (lane & 15);
    const int h0 = ht * 32 + (lane >> 4) * 8;

    f16x8 v;
    #pragma unroll
    for (int j = 0; j < 8; ++j) {
        int h = h0 + j;
        float wv = (h < H && k < H) ? W[((size_t)p * H + h) * H + k] : 0.f;
        v[j] = (_Float16)wv;
    }
    *(f16x8*)(wfrag + (size_t)fb * 512 + (size_t)lane * 8) = v;
}

// ---------------- prep_a: node_attr -> instruction-scaled fragment-ordered fp16 ----
// Unit u(b,nb,p,ht,nt) = ((b*NB+nb)*P+p)*20 + ht*2 + nt; elem = u*512 + lane*8 + j,
// where row = nt*16 + (lane&15) (within 32-row block), h = ht*32 + (lane>>4)*8 + j.
__global__ __launch_bounds__(256)
void nsm_prep_a(const float* __restrict__ node_attr,
                const float* __restrict__ instruction,
                _Float16* __restrict__ afrag)
{
    __shared__ _Float16 sA[NT * SAP];

    const int t  = threadIdx.x;
    const int nb = blockIdx.x;
    const int b  = blockIdx.y;
    const int p  = blockIdx.z;
    const int r  = t >> 3;                 // 0..31 row
    const int cs = t & 7;                  // float4 slot group

    const float* srcA = node_attr + ((size_t)((b * N + nb * NT + r) * P + p)) * H;
    const float* ins  = instruction + (size_t)b * H;

    #pragma unroll
    for (int i = 0; i < 10; ++i) {
        int s = cs + i * 8;                // float4 slot 0..79
        int h = s * 4;
        _Float16 o0 = (_Float16)0.f, o1 = o0, o2 = o0, o3 = o0;
        if (s < 75) {                      // h+3 <= 299
            float4 v  = *(const float4*)(srcA + h);
            float4 sc = *(const float4*)(ins + h);
            o0 = (_Float16)(v.x * sc.x);
            o1 = (_Float16)(v.y * sc.y);
            o2 = (_Float16)(v.z * sc.z);
            o3 = (_Float16)(v.w * sc.w);
        }
        sA[r * SAP + h]     = o0;
        sA[r * SAP + h + 1] = o1;
        sA[r * SAP + h + 2] = o2;
        sA[r * SAP + h + 3] = o3;
    }
    __syncthreads();

    const int w = t >> 6;
    const int l = t & 63;
    const size_t unit_base = ((size_t)(b * NB + nb) * P + p) * 20;
    #pragma unroll
    for (int uu = 0; uu < 5; ++uu) {
        int u  = w + uu * 4;               // 0..19
        int ht = u >> 1;
        int nt = u & 1;
        f16x8 v = *(const f16x8*)&sA[(nt * 16 + (l & 15)) * SAP + ht * 32 + (l >> 4) * 8];
        *(f16x8*)(afrag + (unit_base + u) * 512 + (size_t)l * 8) = v;
    }
}

// ---------------- main: barrier-free MFMA, S1/S2 over P in registers ----------------
__global__ __launch_bounds__(256, 2)
void nsm_scores_mfma(const _Float16* __restrict__ afrag,
                     const _Float16* __restrict__ wfrag,
                     const float* __restrict__ nps,
                     const float* __restrict__ w_state,
                     float* __restrict__ scores)
{
    const int t  = threadIdx.x;
    const int nb = blockIdx.x;
    const int b  = blockIdx.y;
    const int w  = t >> 6;                 // wave: k-range [80w, 80w+80)
    const int l  = t & 63;

    const _Float16* Ab = afrag + ((size_t)(b * NB + nb) * P) * 10240 + (size_t)l * 8;
    const _Float16* Wb = wfrag + (size_t)(w * 5) * 512 + (size_t)l * 8;

    f32x4 S1[2][5], S2[2][5];
    #pragma unroll
    for (int nt = 0; nt < 2; ++nt)
        #pragma unroll
        for (int kt = 0; kt < 5; ++kt) {
            S1[nt][kt] = (f32x4){0.f, 0.f, 0.f, 0.f};
            S2[nt][kt] = (f32x4){0.f, 0.f, 0.f, 0.f};
        }

    for (int p = 0; p < P; ++p) {
        const _Float16* Ap = Ab + (size_t)p * 10240;
        const _Float16* Wp = Wb + (size_t)p * 102400;

        f32x4 acc[2][5];
        #pragma unroll
        for (int nt = 0; nt < 2; ++nt)
            #pragma unroll
            for (int kt = 0; kt < 5; ++kt)
                acc[nt][kt] = (f32x4){0.f, 0.f, 0.f, 0.f};

        #pragma unroll
        for (int ht = 0; ht < 10; ++ht) {
            f16x8 a0 = *(const f16x8*)(Ap + ht * 1024);
            f16x8 a1 = *(const f16x8*)(Ap + ht * 1024 + 512);
            #pragma unroll
            for (int kt = 0; kt < 5; ++kt) {
                f16x8 wf = *(const f16x8*)(Wp + ht * 10240 + kt * 512);
                acc[0][kt] = __builtin_amdgcn_mfma_f32_16x16x32_f16(a0, wf, acc[0][kt], 0, 0, 0);
                acc[1][kt] = __builtin_amdgcn_mfma_f32_16x16x32_f16(a1, wf, acc[1][kt], 0, 0, 0);
            }
        }

        const float sim = nps[b * P + p];
        #pragma unroll
        for (int nt = 0; nt < 2; ++nt)
            #pragma unroll
            for (int kt = 0; kt < 5; ++kt) {
                f32x4 z = acc[nt][kt] * sim;
                S1[nt][kt] += z;
                S2[nt][kt] += z * z;
            }
    }

    // epilogue: normalize over P, elu, dot w_state, reduce over k, atomic add
    // C/D layout: col(k) = l&15, row(n) = (l>>4)*4 + j
    #pragma unroll
    for (int nt = 0; nt < 2; ++nt) {
        #pragma unroll
        for (int j = 0; j < 4; ++j) {
            float part = 0.f;
            #pragma unroll
            for (int kt = 0; kt < 5; ++kt) {
                int k = w * 80 + kt * 16 + (l & 15);
                if (k < H) {
                    float s1 = S1[nt][kt][j];
                    float s2 = S2[nt][kt][j];
                    float denom = fmaxf(sqrtf(s2), EPSN);
                    float v = s1 / denom;
                    float e = v > 0.f ? v : expm1f(v);
                    part += e * w_state[k];
                }
            }
            part += __shfl_xor(part, 1, 16);
            part += __shfl_xor(part, 2, 16);
            part += __shfl_xor(part, 4, 16);
            part += __shfl_xor(part, 8, 16);
            if ((l & 15) == 0)
                atomicAdd(&scores[b * N + nb * NT + nt * 16 + (l >> 4) * 4 + j], part);
        }
    }
}

__global__ __launch_bounds__(256)
void nsm_softmax_kernel(float* __restrict__ out, const float* __restrict__ mask)
{
    __shared__ float redm[4];
    __shared__ float reds[4];
    const int b = blockIdx.x;
    const int t = threadIdx.x;

    float v0 = out[b * N + t]       + mask[b * N + t];
    float v1 = out[b * N + 256 + t] + mask[b * N + 256 + t];

    float m = fmaxf(v0, v1);
    m = fmaxf(m, __shfl_xor(m, 1, 64));
    m = fmaxf(m, __shfl_xor(m, 2, 64));
    m = fmaxf(m, __shfl_xor(m, 4, 64));
    m = fmaxf(m, __shfl_xor(m, 8, 64));
    m = fmaxf(m, __shfl_xor(m, 16, 64));
    m = fmaxf(m, __shfl_xor(m, 32, 64));
    const int wave = t >> 6;
    const int lane = t & 63;
    if (lane == 0) redm[wave] = m;
    __syncthreads();
    m = fmaxf(fmaxf(redm[0], redm[1]), fmaxf(redm[2], redm[3]));

    float e0 = expf(v0 - m);
    float e1 = expf(v1 - m);
    float s = e0 + e1;
    s += __shfl_xor(s, 1, 64);
    s += __shfl_xor(s, 2, 64);
    s += __shfl_xor(s, 4, 64);
    s += __shfl_xor(s, 8, 64);
    s += __shfl_xor(s, 16, 64);
    s += __shfl_xor(s, 32, 64);
    if (lane == 0) reds[wave] = s;
    __syncthreads();
    s = reds[0] + reds[1] + reds[2] + reds[3];

    out[b * N + t]       = e0 / s;
    out[b * N + 256 + t] = e1 / s;
}

extern "C" void kernel_launch(void* const* d_in, const int* in_sizes, int n_in,
                              void* d_out, int out_size, void* d_ws, size_t ws_size,
                              hipStream_t stream)
{
    const float* node_attr   = (const float*)d_in[0];
    const float* instruction = (const float*)d_in[2];
    const float* nps         = (const float*)d_in[5];
    const float* node_mask   = (const float*)d_in[6];
    const float* W_node      = (const float*)d_in[7];
    const float* w_state     = (const float*)d_in[8];
    float* out = (float*)d_out;

    _Float16* afrag = (_Float16*)d_ws;                      // 41.9M halfs = 83.9 MB
    _Float16* wfrag = afrag + (size_t)B * NB * P * 20 * 512;  // 1600*512 halfs = 1.64 MB

    nsm_prep_w<<<dim3(400), 256, 0, stream>>>(W_node, wfrag);
    nsm_prep_a<<<dim3(NB, B, P), 256, 0, stream>>>(node_attr, instruction, afrag);

    (void)hipMemsetAsync(out, 0, (size_t)B * N * sizeof(float), stream);

    dim3 grid(NB, B);   // (16, 32) = 512 blocks
    nsm_scores_mfma<<<grid, 256, 0, stream>>>(afrag, wfrag, nps, w_state, out);
    nsm_softmax_kernel<<<dim3(B), 256, 0, stream>>>(out, node_mask);
}